// Round 6
// baseline (1425.234 us; speedup 1.0000x reference)
//
#include <hip/hip_runtime.h>

#define NN 100000
#define NE 1600000
#define HD 128
#define EPSV 1e-8f
#define EB 128      // edges per tile
#define NTILES (NE / EB)          // 12500
#define EGRID 750                 // k_edge blocks; 500 blocks x17 + 250 x16 tiles
#define LPAD 136    // padded LDS row (bf16 elems): 272 B, 16B-aligned
#define CPAD 264    // padded row for 256-wide concat tile

typedef unsigned short ushort_t;
typedef __attribute__((ext_vector_type(8))) short bf16x8;
typedef __attribute__((ext_vector_type(4))) float f32x4;

__device__ __forceinline__ float silu_f(float x) {
    return x * __builtin_amdgcn_rcpf(1.0f + __expf(-x));
}
__device__ __forceinline__ float b2f(unsigned short u) {
    union { unsigned int i; float f; } v; v.i = ((unsigned int)u) << 16; return v.f;
}
__device__ __forceinline__ unsigned short f2b(float f) {
    union { float f; unsigned int i; } v; v.f = f;
    unsigned int r = v.i + 0x7fff + ((v.i >> 16) & 1);
    return (unsigned short)(r >> 16);
}
__device__ __forceinline__ unsigned int cvt_pk_bf16(float lo, float hi) {
    unsigned int r;
    asm("v_cvt_pk_bf16_f32 %0, %1, %2" : "=v"(r) : "v"(lo), "v"(hi));
    return r;
}

// ---------------------------------------------------------------------------
// Kernel 0: build bf16 transposed weight tables.
// ---------------------------------------------------------------------------
extern "C" __global__ __launch_bounds__(256)
void k_prep(const float* __restrict__ We2, const float* __restrict__ Wc1,
            const float* __restrict__ We1, const float* __restrict__ Wn1,
            const float* __restrict__ Wn2,
            ushort_t* __restrict__ We2T, ushort_t* __restrict__ Wc1T,
            ushort_t* __restrict__ WabT, ushort_t* __restrict__ Wn1T,
            ushort_t* __restrict__ Wn2T)
{
    int id = blockIdx.x * 256 + threadIdx.x;
    if (id < 16384) {
        int n = id >> 7, k = id & 127;
        We2T[id] = f2b(We2[k * HD + n]);
    } else if (id < 32768) {
        int r = id - 16384; int n = r >> 7, k = r & 127;
        Wc1T[r] = f2b(Wc1[k * HD + n]);
    } else if (id < 65536) {
        int r = id - 32768; int j = r >> 7, k = r & 127;
        float v = (j < 128) ? We1[k * HD + j] : We1[(size_t)(128 + k) * HD + (j - 128)];
        WabT[r] = f2b(v);
    } else if (id < 98304) {
        int r = id - 65536; int j = r >> 8, k = r & 255;
        Wn1T[r] = f2b(Wn1[(size_t)k * HD + j]);
    } else if (id < 114688) {
        int r = id - 98304; int j = r >> 7, k = r & 127;
        Wn2T[r] = f2b(Wn2[k * HD + j]);
    }
}

// ---------------------------------------------------------------------------
// Sort: histogram -> 3-kernel parallel scan -> scatter pre-gathered (row,col)
// ---------------------------------------------------------------------------
extern "C" __global__ __launch_bounds__(256)
void k_hist(const int* __restrict__ ei, int* __restrict__ deg)
{
    int e = blockIdx.x * 256 + threadIdx.x;
    atomicAdd(&deg[ei[e]], 1);
}

extern "C" __global__ __launch_bounds__(1024)
void k_scan1(const int* __restrict__ deg, int* __restrict__ bsum)
{
    __shared__ int wsum[16];
    const int tid = threadIdx.x;
    const int lane = tid & 63, w = tid >> 6;
    int i = blockIdx.x * 1024 + tid;
    int v = (i < NN) ? deg[i] : 0;
#pragma unroll
    for (int off = 32; off > 0; off >>= 1) v += __shfl_xor(v, off, 64);
    if (lane == 0) wsum[w] = v;
    __syncthreads();
    if (tid == 0) {
        int s = 0;
#pragma unroll
        for (int k = 0; k < 16; k++) s += wsum[k];
        bsum[blockIdx.x] = s;
    }
}

extern "C" __global__ __launch_bounds__(128)
void k_scan2(const int* __restrict__ bsum, int* __restrict__ boff, int nb)
{
    __shared__ int wsum2[2];
    const int tid = threadIdx.x;
    const int lane = tid & 63, w = tid >> 6;
    int v = (tid < nb) ? bsum[tid] : 0;
    int s = v;
#pragma unroll
    for (int off = 1; off < 64; off <<= 1) {
        int t = __shfl_up(s, off, 64);
        if (lane >= off) s += t;
    }
    if (lane == 63) wsum2[w] = s;
    __syncthreads();
    int excl = ((w == 1) ? wsum2[0] : 0) + s - v;
    if (tid < nb) boff[tid] = excl;
}

extern "C" __global__ __launch_bounds__(1024)
void k_scan3(const int* __restrict__ deg, const int* __restrict__ boff,
             int* __restrict__ cursor)
{
    __shared__ int wsum[16];
    const int tid = threadIdx.x;
    const int lane = tid & 63, w = tid >> 6;
    int i = blockIdx.x * 1024 + tid;
    int v = (i < NN) ? deg[i] : 0;
    int s = v;
#pragma unroll
    for (int off = 1; off < 64; off <<= 1) {
        int t = __shfl_up(s, off, 64);
        if (lane >= off) s += t;
    }
    if (lane == 63) wsum[w] = s;
    __syncthreads();
    if (w == 0) {
        int ws = (lane < 16) ? wsum[lane] : 0;
#pragma unroll
        for (int off = 1; off < 16; off <<= 1) {
            int t = __shfl_up(ws, off, 64);
            if (lane >= off) ws += t;
        }
        if (lane < 16) wsum[lane] = ws;
    }
    __syncthreads();
    int excl = boff[blockIdx.x] + ((w > 0) ? wsum[w - 1] : 0) + s - v;
    if (i < NN) cursor[i] = excl;
}

extern "C" __global__ __launch_bounds__(256)
void k_sortids(const int* __restrict__ ei, int* __restrict__ cursor,
               int2* __restrict__ rc)
{
    int e = blockIdx.x * 256 + threadIdx.x;
    int r = ei[e], c = ei[NE + e];
    int slot = atomicAdd(&cursor[r], 1);
    rc[slot] = make_int2(r, c);
}

// ---------------------------------------------------------------------------
// Kernel 1: MFMA  [A|B] = bf16(h) @ Wab (+be1 on A half). Operand-swapped:
// lane holds 4 consecutive output features for node lr -> packed b64 stores.
// ---------------------------------------------------------------------------
extern "C" __global__ __launch_bounds__(256)
void k_ab(const float* __restrict__ h, const ushort_t* __restrict__ WabT,
          const float* __restrict__ be1,
          ushort_t* __restrict__ A, ushort_t* __restrict__ B)
{
    __shared__ ushort_t hs[64][LPAD] __attribute__((aligned(16)));
    const int tid = threadIdx.x;
    const int n0 = blockIdx.x * 64;
    {
        int r = tid >> 2, seg = tid & 3;
        int n = n0 + r; if (n >= NN) n = n0;
        const float4* src = (const float4*)(h + (size_t)n * HD + seg * 32);
        uint2* dst = (uint2*)&hs[r][seg * 32];
#pragma unroll
        for (int i = 0; i < 8; i++) {
            float4 v = src[i];
            uint2 p; p.x = cvt_pk_bf16(v.x, v.y); p.y = cvt_pk_bf16(v.z, v.w);
            dst[i] = p;
        }
    }
    __syncthreads();
    const int wave = tid >> 6, lane = tid & 63;
    const int lr = lane & 15, lg = lane >> 4;
    f32x4 acc[16];
#pragma unroll
    for (int nt = 0; nt < 16; nt++) acc[nt] = (f32x4){0.f, 0.f, 0.f, 0.f};
#pragma unroll
    for (int ks = 0; ks < 4; ks++) {
        bf16x8 hf8 = *(const bf16x8*)&hs[wave * 16 + lr][ks * 32 + lg * 8];
#pragma unroll
        for (int nt = 0; nt < 16; nt++) {
            bf16x8 wf = *(const bf16x8*)(WabT + (size_t)(nt * 16 + lr) * HD + ks * 32 + lg * 8);
            acc[nt] = __builtin_amdgcn_mfma_f32_16x16x32_bf16(wf, hf8, acc[nt], 0, 0, 0);
        }
    }
    const int node = n0 + wave * 16 + lr;
    if (node < NN) {
#pragma unroll
        for (int nt = 0; nt < 16; nt++) {
            float4 bias = (nt < 8) ? ((const float4*)be1)[nt * 4 + lg]
                                   : (float4){0.f, 0.f, 0.f, 0.f};
            uint2 pk;
            pk.x = cvt_pk_bf16(acc[nt][0] + bias.x, acc[nt][1] + bias.y);
            pk.y = cvt_pk_bf16(acc[nt][2] + bias.z, acc[nt][3] + bias.w);
            if (nt < 8)
                *(uint2*)(A + (size_t)node * HD + nt * 16 + lg * 4) = pk;
            else
                *(uint2*)(B + (size_t)node * HD + (nt - 8) * 16 + lg * 4) = pk;
        }
    }
}

// ---------------------------------------------------------------------------
// Kernel 2: persistent pipelined MFMA edge kernel over sorted rc[].
// Per block: ~16-17 consecutive 128-edge tiles; B[col] rows register-
// prefetched one tile ahead. All MFMAs operand-swapped.
// ---------------------------------------------------------------------------
extern "C" __global__ __launch_bounds__(256, 3)
void k_edge(const int2* __restrict__ rc, const float* __restrict__ coord,
            const ushort_t* __restrict__ A, const ushort_t* __restrict__ B,
            const float* __restrict__ WeL, const float* __restrict__ be2,
            const ushort_t* __restrict__ We2T,
            const ushort_t* __restrict__ Wc1T,
            const float* __restrict__ bc1, const float* __restrict__ Wc2,
            float* __restrict__ agg_h, float* __restrict__ agg_c)
{
    __shared__ ushort_t m_lds[EB][LPAD] __attribute__((aligned(16)));
    __shared__ float cd_lds[EB][4];
    __shared__ int rows_s[EB];

    const int tid = threadIdx.x;
    const int e  = tid >> 1;       // edge slot 0..127
    const int hf = tid & 1;        // feature half
    const int wave = tid >> 6, lane = tid & 63;
    const int lr = lane & 15, lg = lane >> 4;

    const int b = blockIdx.x;
    const int t0  = b * 16 + ((b < 500) ? b : 500);
    const int ntl = (b < 500) ? 17 : 16;

    // ---- prologue: load tile 0's edge data + B rows into registers ----
    int2 rc0 = rc[t0 * EB + e];
    int row = rc0.x, col = rc0.y;
    float crx = coord[(size_t)row * 3 + 0], cry = coord[(size_t)row * 3 + 1],
          crz = coord[(size_t)row * 3 + 2];
    float ccx = coord[(size_t)col * 3 + 0], ccy = coord[(size_t)col * 3 + 1],
          ccz = coord[(size_t)col * 3 + 2];
    bf16x8 Bst[8];
    {
        const bf16x8* Bp = (const bf16x8*)(B + (size_t)col * HD + hf * 64);
#pragma unroll
        for (int i = 0; i < 8; i++) Bst[i] = Bp[i];
    }

    for (int t = 0; t < ntl; t++) {
        // ---- phase 0: coord/radial, m1 -> LDS (wave-local rows) ----
        float c0 = crx - ccx, c1 = cry - ccy, c2 = crz - ccz;
        float radial = c0 * c0 + c1 * c1 + c2 * c2;
        if (hf == 0) {
            rows_s[e] = row;
            float inv = __builtin_amdgcn_rcpf(sqrtf(radial) + EPSV);
            cd_lds[e][0] = c0 * inv; cd_lds[e][1] = c1 * inv; cd_lds[e][2] = c2 * inv;
        }
        {
            const bf16x8* A8 = (const bf16x8*)(A + (size_t)row * HD + hf * 64);
            const float4* WL4 = (const float4*)WeL + hf * 16;
#pragma unroll
            for (int i = 0; i < 8; i++) {
                bf16x8 av = A8[i], bv = Bst[i];
                float4 w0 = WL4[2 * i], w1 = WL4[2 * i + 1];
                float v0 = silu_f(b2f((ushort_t)av[0]) + b2f((ushort_t)bv[0]) + radial * w0.x);
                float v1 = silu_f(b2f((ushort_t)av[1]) + b2f((ushort_t)bv[1]) + radial * w0.y);
                float v2 = silu_f(b2f((ushort_t)av[2]) + b2f((ushort_t)bv[2]) + radial * w0.z);
                float v3 = silu_f(b2f((ushort_t)av[3]) + b2f((ushort_t)bv[3]) + radial * w0.w);
                float v4 = silu_f(b2f((ushort_t)av[4]) + b2f((ushort_t)bv[4]) + radial * w1.x);
                float v5 = silu_f(b2f((ushort_t)av[5]) + b2f((ushort_t)bv[5]) + radial * w1.y);
                float v6 = silu_f(b2f((ushort_t)av[6]) + b2f((ushort_t)bv[6]) + radial * w1.z);
                float v7 = silu_f(b2f((ushort_t)av[7]) + b2f((ushort_t)bv[7]) + radial * w1.w);
                uint4 p;
                p.x = cvt_pk_bf16(v0, v1); p.y = cvt_pk_bf16(v2, v3);
                p.z = cvt_pk_bf16(v4, v5); p.w = cvt_pk_bf16(v6, v7);
                *(uint4*)&m_lds[e][hf * 64 + i * 8] = p;
            }
        }
        // ---- issue next tile's loads (lands during the GEMMs below) ----
        if (t + 1 < ntl) {
            int2 rcn = rc[(t0 + t + 1) * EB + e];
            row = rcn.x; col = rcn.y;
            crx = coord[(size_t)row * 3 + 0]; cry = coord[(size_t)row * 3 + 1];
            crz = coord[(size_t)row * 3 + 2];
            ccx = coord[(size_t)col * 3 + 0]; ccy = coord[(size_t)col * 3 + 1];
            ccz = coord[(size_t)col * 3 + 2];
            const bf16x8* Bp = (const bf16x8*)(B + (size_t)col * HD + hf * 64);
#pragma unroll
            for (int i = 0; i < 8; i++) Bst[i] = Bp[i];
        }

        // ---- GEMM1 (swapped): lane -> m[edge=lr(+16mt)][4 consecutive j] ----
        f32x4 acc[2][8];
#pragma unroll
        for (int mt = 0; mt < 2; mt++)
#pragma unroll
            for (int nt = 0; nt < 8; nt++) acc[mt][nt] = (f32x4){0.f, 0.f, 0.f, 0.f};
#pragma unroll
        for (int ks = 0; ks < 4; ks++) {
            bf16x8 mf0 = *(const bf16x8*)&m_lds[wave * 32 + lr][ks * 32 + lg * 8];
            bf16x8 mf1 = *(const bf16x8*)&m_lds[wave * 32 + 16 + lr][ks * 32 + lg * 8];
#pragma unroll
            for (int nt = 0; nt < 8; nt++) {
                bf16x8 wf = *(const bf16x8*)(We2T + (size_t)(nt * 16 + lr) * HD + ks * 32 + lg * 8);
                acc[0][nt] = __builtin_amdgcn_mfma_f32_16x16x32_bf16(wf, mf0, acc[0][nt], 0, 0, 0);
                acc[1][nt] = __builtin_amdgcn_mfma_f32_16x16x32_bf16(wf, mf1, acc[1][nt], 0, 0, 0);
            }
        }
        // m = silu(acc+be2) -> m_lds[edge][j], b64 packed (wave-local rows)
#pragma unroll
        for (int nt = 0; nt < 8; nt++) {
            float4 be2v = ((const float4*)be2)[nt * 4 + lg];
#pragma unroll
            for (int mt = 0; mt < 2; mt++) {
                float v0 = silu_f(acc[mt][nt][0] + be2v.x);
                float v1 = silu_f(acc[mt][nt][1] + be2v.y);
                float v2 = silu_f(acc[mt][nt][2] + be2v.z);
                float v3 = silu_f(acc[mt][nt][3] + be2v.w);
                uint2 pk; pk.x = cvt_pk_bf16(v0, v1); pk.y = cvt_pk_bf16(v2, v3);
                *(uint2*)&m_lds[wave * 32 + mt * 16 + lr][nt * 16 + lg * 4] = pk;
            }
        }

        // ---- GEMM2 (swapped): m @ Wc1 ----
#pragma unroll
        for (int mt = 0; mt < 2; mt++)
#pragma unroll
            for (int nt = 0; nt < 8; nt++) acc[mt][nt] = (f32x4){0.f, 0.f, 0.f, 0.f};
#pragma unroll
        for (int ks = 0; ks < 4; ks++) {
            bf16x8 mf0 = *(const bf16x8*)&m_lds[wave * 32 + lr][ks * 32 + lg * 8];
            bf16x8 mf1 = *(const bf16x8*)&m_lds[wave * 32 + 16 + lr][ks * 32 + lg * 8];
#pragma unroll
            for (int nt = 0; nt < 8; nt++) {
                bf16x8 wf = *(const bf16x8*)(Wc1T + (size_t)(nt * 16 + lr) * HD + ks * 32 + lg * 8);
                acc[0][nt] = __builtin_amdgcn_mfma_f32_16x16x32_bf16(wf, mf0, acc[0][nt], 0, 0, 0);
                acc[1][nt] = __builtin_amdgcn_mfma_f32_16x16x32_bf16(wf, mf1, acc[1][nt], 0, 0, 0);
            }
        }

        // phi[e] = sum_j silu(u+bc1)*Wc2 ; per-lane partial over its 4 j's
        float ph0 = 0.f, ph1 = 0.f;
#pragma unroll
        for (int nt = 0; nt < 8; nt++) {
            float4 bc1v = ((const float4*)bc1)[nt * 4 + lg];
            float4 wc2v = ((const float4*)Wc2)[nt * 4 + lg];
            ph0 += silu_f(acc[0][nt][0] + bc1v.x) * wc2v.x
                 + silu_f(acc[0][nt][1] + bc1v.y) * wc2v.y
                 + silu_f(acc[0][nt][2] + bc1v.z) * wc2v.z
                 + silu_f(acc[0][nt][3] + bc1v.w) * wc2v.w;
            ph1 += silu_f(acc[1][nt][0] + bc1v.x) * wc2v.x
                 + silu_f(acc[1][nt][1] + bc1v.y) * wc2v.y
                 + silu_f(acc[1][nt][2] + bc1v.z) * wc2v.z
                 + silu_f(acc[1][nt][3] + bc1v.w) * wc2v.w;
        }
        ph0 += __shfl_xor(ph0, 16, 64); ph0 += __shfl_xor(ph0, 32, 64);
        ph1 += __shfl_xor(ph1, 16, 64); ph1 += __shfl_xor(ph1, 32, 64);
        if (lg == 0) {
            int e0 = wave * 32 + lr, e1 = e0 + 16;
            cd_lds[e0][0] *= ph0; cd_lds[e0][1] *= ph0; cd_lds[e0][2] *= ph0;
            cd_lds[e1][0] *= ph1; cd_lds[e1][1] *= ph1; cd_lds[e1][2] *= ph1;
        }

        __syncthreads();   // scatter reads all waves' rows

        // ---- agg_h: run-merged scatter (rows sorted) ----
        {
            const int j = tid & 127, g = tid >> 7;
            const int es0 = g * 64, es1 = es0 + 64;
            float acc_r = 0.f;
            int cur = rows_s[es0];
            for (int es = es0; es < es1; es++) {
                int r = rows_s[es];
                if (r != cur) {
                    atomicAdd(&agg_h[(size_t)cur * HD + j], acc_r);
                    acc_r = 0.f; cur = r;
                }
                acc_r += b2f(m_lds[es][j]);
            }
            atomicAdd(&agg_h[(size_t)cur * HD + j], acc_r);
        }
        // ---- agg_c: run-merge, wave 0 only ----
        if (wave == 0) {
            int c = lane >> 4, sub = lane & 15;
            if (c < 3) {
                const int es0 = sub * 8, es1 = es0 + 8;
                float acc_r = 0.f;
                int cur = rows_s[es0];
                for (int es = es0; es < es1; es++) {
                    int r = rows_s[es];
                    if (r != cur) {
                        atomicAdd(&agg_c[(size_t)cur * 3 + c], acc_r);
                        acc_r = 0.f; cur = r;
                    }
                    acc_r += cd_lds[es][c];
                }
                atomicAdd(&agg_c[(size_t)cur * 3 + c], acc_r);
            }
        }
        __syncthreads();   // protect m_lds/cd_lds/rows_s before next phase 0
    }
}

// ---------------------------------------------------------------------------
// Kernel 3: MFMA node MLP (operand-swapped), float4 residual epilogue.
// ---------------------------------------------------------------------------
extern "C" __global__ __launch_bounds__(256)
void k_node(const float* __restrict__ h, const ushort_t* __restrict__ Wn1T,
            const float* __restrict__ bn1, const ushort_t* __restrict__ Wn2T,
            const float* __restrict__ bn2, const float* __restrict__ coord,
            const int* __restrict__ deg,
            float* __restrict__ hout /* = agg_h in */,
            float* __restrict__ cout /* = agg_c in */)
{
    __shared__ ushort_t cs[64][CPAD] __attribute__((aligned(16)));
    __shared__ ushort_t us[64][LPAD] __attribute__((aligned(16)));
    const int tid = threadIdx.x;
    const int n0 = blockIdx.x * 64;
    {
        int r = tid >> 2, seg = tid & 3;
        int n = n0 + r; if (n >= NN) n = n0;
        const float4* s0 = (const float4*)(h + (size_t)n * HD + seg * 32);
        const float4* s1 = (const float4*)(hout + (size_t)n * HD + seg * 32);
        uint2* d0 = (uint2*)&cs[r][seg * 32];
        uint2* d1 = (uint2*)&cs[r][128 + seg * 32];
#pragma unroll
        for (int i = 0; i < 8; i++) {
            float4 v = s0[i];
            uint2 p; p.x = cvt_pk_bf16(v.x, v.y); p.y = cvt_pk_bf16(v.z, v.w);
            d0[i] = p;
            float4 w = s1[i];
            uint2 q; q.x = cvt_pk_bf16(w.x, w.y); q.y = cvt_pk_bf16(w.z, w.w);
            d1[i] = q;
        }
    }
    __syncthreads();
    const int wave = tid >> 6, lane = tid & 63;
    const int lr = lane & 15, lg = lane >> 4;

    // ---- GEMM1 (swapped): cat[64,256] @ Wn1 -> u ----
    f32x4 acc[8];
#pragma unroll
    for (int nt = 0; nt < 8; nt++) acc[nt] = (f32x4){0.f, 0.f, 0.f, 0.f};
#pragma unroll
    for (int ks = 0; ks < 8; ks++) {
        bf16x8 cf = *(const bf16x8*)&cs[wave * 16 + lr][ks * 32 + lg * 8];
#pragma unroll
        for (int nt = 0; nt < 8; nt++) {
            bf16x8 wf = *(const bf16x8*)(Wn1T + (size_t)(nt * 16 + lr) * 256 + ks * 32 + lg * 8);
            acc[nt] = __builtin_amdgcn_mfma_f32_16x16x32_bf16(wf, cf, acc[nt], 0, 0, 0);
        }
    }
#pragma unroll
    for (int nt = 0; nt < 8; nt++) {
        float4 b1 = ((const float4*)bn1)[nt * 4 + lg];
        float v0 = silu_f(acc[nt][0] + b1.x);
        float v1 = silu_f(acc[nt][1] + b1.y);
        float v2 = silu_f(acc[nt][2] + b1.z);
        float v3 = silu_f(acc[nt][3] + b1.w);
        uint2 pk; pk.x = cvt_pk_bf16(v0, v1); pk.y = cvt_pk_bf16(v2, v3);
        *(uint2*)&us[wave * 16 + lr][nt * 16 + lg * 4] = pk;
    }
    // wave-local rows -> no barrier

    // ---- GEMM2 (swapped): u[64,128] @ Wn2 ----
    f32x4 acc2[8];
#pragma unroll
    for (int nt = 0; nt < 8; nt++) acc2[nt] = (f32x4){0.f, 0.f, 0.f, 0.f};
#pragma unroll
    for (int ks = 0; ks < 4; ks++) {
        bf16x8 uf = *(const bf16x8*)&us[wave * 16 + lr][ks * 32 + lg * 8];
#pragma unroll
        for (int nt = 0; nt < 8; nt++) {
            bf16x8 wf = *(const bf16x8*)(Wn2T + (size_t)(nt * 16 + lr) * HD + ks * 32 + lg * 8);
            acc2[nt] = __builtin_amdgcn_mfma_f32_16x16x32_bf16(wf, uf, acc2[nt], 0, 0, 0);
        }
    }
    const int node = n0 + wave * 16 + lr;
    if (node < NN) {
#pragma unroll
        for (int nt = 0; nt < 8; nt++) {
            float4 b2 = ((const float4*)bn2)[nt * 4 + lg];
            size_t idx = (size_t)node * HD + nt * 16 + lg * 4;
            float4 hv = *(const float4*)(h + idx);
            float4 o;
            o.x = hv.x + acc2[nt][0] + b2.x;
            o.y = hv.y + acc2[nt][1] + b2.y;
            o.z = hv.z + acc2[nt][2] + b2.z;
            o.w = hv.w + acc2[nt][3] + b2.w;
            *(float4*)(hout + idx) = o;
        }
        if (lg == 0) {
            float invc = __builtin_amdgcn_rcpf(fmaxf((float)deg[node], 1.0f));
#pragma unroll
            for (int i = 0; i < 3; i++) {
                size_t idx = (size_t)node * 3 + i;
                cout[idx] = coord[idx] + cout[idx] * invc;
            }
        }
    }
}

// ---------------------------------------------------------------------------
extern "C" void kernel_launch(void* const* d_in, const int* in_sizes, int n_in,
                              void* d_out, int out_size, void* d_ws, size_t ws_size,
                              hipStream_t stream)
{
    const float* h     = (const float*)d_in[0];
    const int*   ei    = (const int*)d_in[1];
    const float* coord = (const float*)d_in[2];
    const float* We1   = (const float*)d_in[3];
    const float* be1   = (const float*)d_in[4];
    const float* We2   = (const float*)d_in[5];
    const float* be2   = (const float*)d_in[6];
    const float* Wn1   = (const float*)d_in[7];
    const float* bn1   = (const float*)d_in[8];
    const float* Wn2   = (const float*)d_in[9];
    const float* bn2   = (const float*)d_in[10];
    const float* Wc1   = (const float*)d_in[11];
    const float* bc1   = (const float*)d_in[12];
    const float* Wc2   = (const float*)d_in[13];

    float* out   = (float*)d_out;
    float* agg_h = out;                         // [NN,128] accum, then h_out
    float* agg_c = out + (size_t)NN * HD;       // [NN,3]  accum, then coord_out

    ushort_t* A    = (ushort_t*)d_ws;            // [NN,128] bf16
    ushort_t* B    = A + (size_t)NN * HD;        // [NN,128] bf16
    ushort_t* We2T = B + (size_t)NN * HD;        // [128,128]
    ushort_t* Wc1T = We2T + 16384;               // [128,128]
    ushort_t* WabT = Wc1T + 16384;               // [256,128]
    ushort_t* Wn1T = WabT + 32768;               // [128,256]
    ushort_t* Wn2T = Wn1T + 32768;               // [128,128]
    int* deg    = (int*)(Wn2T + 16384);          // [NN]
    int* cursor = deg + NN;                      // [NN]
    int* bsum   = cursor + NN;                   // [98]
    int* boff   = bsum + 128;                    // [98]
    int2* rc    = (int2*)(boff + 128);           // [NE] pre-gathered (row,col)
    const float* WeL = We1 + (size_t)2 * HD * HD;

    const int scan_nb = (NN + 1023) / 1024;      // 98

    hipMemsetAsync(d_out, 0, (size_t)out_size * sizeof(float), stream);
    hipMemsetAsync(deg, 0, (size_t)NN * sizeof(int), stream);

    k_prep<<<448, 256, 0, stream>>>(We2, Wc1, We1, Wn1, Wn2,
                                    We2T, Wc1T, WabT, Wn1T, Wn2T);
    k_hist<<<NE / 256, 256, 0, stream>>>(ei, deg);
    k_ab<<<(NN + 63) / 64, 256, 0, stream>>>(h, WabT, be1, A, B);
    k_scan1<<<scan_nb, 1024, 0, stream>>>(deg, bsum);
    k_scan2<<<1, 128, 0, stream>>>(bsum, boff, scan_nb);
    k_scan3<<<scan_nb, 1024, 0, stream>>>(deg, boff, cursor);
    k_sortids<<<NE / 256, 256, 0, stream>>>(ei, cursor, rc);
    k_edge<<<EGRID, 256, 0, stream>>>(rc, coord, A, B, WeL, be2,
                                      We2T, Wc1T, bc1, Wc2, agg_h, agg_c);
    k_node<<<(NN + 63) / 64, 256, 0, stream>>>(h, Wn1T, bn1, Wn2T, bn2, coord,
                                               deg, agg_h, agg_c);
}

// Round 7
// 1043.692 us; speedup vs baseline: 1.3656x; 1.3656x over previous
//
#include <hip/hip_runtime.h>

#define NN 100000
#define NE 1600000
#define HD 128
#define EPSV 1e-8f
#define EB 128      // edges per block
#define LPAD 136    // padded LDS row (bf16 elems): 272 B, 16B-aligned
#define CPAD 264    // padded row for 256-wide concat tile

typedef unsigned short ushort_t;
typedef __attribute__((ext_vector_type(8))) short bf16x8;
typedef __attribute__((ext_vector_type(4))) float f32x4;

__device__ __forceinline__ float silu_f(float x) {
    return x * __builtin_amdgcn_rcpf(1.0f + __expf(-x));
}
__device__ __forceinline__ float b2f(unsigned short u) {
    union { unsigned int i; float f; } v; v.i = ((unsigned int)u) << 16; return v.f;
}
__device__ __forceinline__ unsigned short f2b(float f) {
    union { float f; unsigned int i; } v; v.f = f;
    unsigned int r = v.i + 0x7fff + ((v.i >> 16) & 1);
    return (unsigned short)(r >> 16);
}
__device__ __forceinline__ unsigned int cvt_pk_bf16(float lo, float hi) {
    unsigned int r;
    asm("v_cvt_pk_bf16_f32 %0, %1, %2" : "=v"(r) : "v"(lo), "v"(hi));
    return r;
}

// ---------------------------------------------------------------------------
// Kernel 0: build bf16 transposed weight tables.
// ---------------------------------------------------------------------------
extern "C" __global__ __launch_bounds__(256)
void k_prep(const float* __restrict__ We2, const float* __restrict__ Wc1,
            const float* __restrict__ We1, const float* __restrict__ Wn1,
            const float* __restrict__ Wn2,
            ushort_t* __restrict__ We2T, ushort_t* __restrict__ Wc1T,
            ushort_t* __restrict__ WabT, ushort_t* __restrict__ Wn1T,
            ushort_t* __restrict__ Wn2T)
{
    int id = blockIdx.x * 256 + threadIdx.x;
    if (id < 16384) {
        int n = id >> 7, k = id & 127;
        We2T[id] = f2b(We2[k * HD + n]);
    } else if (id < 32768) {
        int r = id - 16384; int n = r >> 7, k = r & 127;
        Wc1T[r] = f2b(Wc1[k * HD + n]);
    } else if (id < 65536) {
        int r = id - 32768; int j = r >> 7, k = r & 127;
        float v = (j < 128) ? We1[k * HD + j] : We1[(size_t)(128 + k) * HD + (j - 128)];
        WabT[r] = f2b(v);
    } else if (id < 98304) {
        int r = id - 65536; int j = r >> 8, k = r & 255;
        Wn1T[r] = f2b(Wn1[(size_t)k * HD + j]);
    } else if (id < 114688) {
        int r = id - 98304; int j = r >> 7, k = r & 127;
        Wn2T[r] = f2b(Wn2[k * HD + j]);
    }
}

// ---------------------------------------------------------------------------
// Sort: histogram -> 3-kernel parallel scan -> scatter pre-gathered (row,col)
// ---------------------------------------------------------------------------
extern "C" __global__ __launch_bounds__(256)
void k_hist(const int* __restrict__ ei, int* __restrict__ deg)
{
    int e = blockIdx.x * 256 + threadIdx.x;
    atomicAdd(&deg[ei[e]], 1);
}

extern "C" __global__ __launch_bounds__(1024)
void k_scan1(const int* __restrict__ deg, int* __restrict__ bsum)
{
    __shared__ int wsum[16];
    const int tid = threadIdx.x;
    const int lane = tid & 63, w = tid >> 6;
    int i = blockIdx.x * 1024 + tid;
    int v = (i < NN) ? deg[i] : 0;
#pragma unroll
    for (int off = 32; off > 0; off >>= 1) v += __shfl_xor(v, off, 64);
    if (lane == 0) wsum[w] = v;
    __syncthreads();
    if (tid == 0) {
        int s = 0;
#pragma unroll
        for (int k = 0; k < 16; k++) s += wsum[k];
        bsum[blockIdx.x] = s;
    }
}

extern "C" __global__ __launch_bounds__(128)
void k_scan2(const int* __restrict__ bsum, int* __restrict__ boff, int nb)
{
    __shared__ int wsum2[2];
    const int tid = threadIdx.x;
    const int lane = tid & 63, w = tid >> 6;
    int v = (tid < nb) ? bsum[tid] : 0;
    int s = v;
#pragma unroll
    for (int off = 1; off < 64; off <<= 1) {
        int t = __shfl_up(s, off, 64);
        if (lane >= off) s += t;
    }
    if (lane == 63) wsum2[w] = s;
    __syncthreads();
    int excl = ((w == 1) ? wsum2[0] : 0) + s - v;
    if (tid < nb) boff[tid] = excl;
}

extern "C" __global__ __launch_bounds__(1024)
void k_scan3(const int* __restrict__ deg, const int* __restrict__ boff,
             int* __restrict__ cursor)
{
    __shared__ int wsum[16];
    const int tid = threadIdx.x;
    const int lane = tid & 63, w = tid >> 6;
    int i = blockIdx.x * 1024 + tid;
    int v = (i < NN) ? deg[i] : 0;
    int s = v;
#pragma unroll
    for (int off = 1; off < 64; off <<= 1) {
        int t = __shfl_up(s, off, 64);
        if (lane >= off) s += t;
    }
    if (lane == 63) wsum[w] = s;
    __syncthreads();
    if (w == 0) {
        int ws = (lane < 16) ? wsum[lane] : 0;
#pragma unroll
        for (int off = 1; off < 16; off <<= 1) {
            int t = __shfl_up(ws, off, 64);
            if (lane >= off) ws += t;
        }
        if (lane < 16) wsum[lane] = ws;
    }
    __syncthreads();
    int excl = boff[blockIdx.x] + ((w > 0) ? wsum[w - 1] : 0) + s - v;
    if (i < NN) cursor[i] = excl;
}

extern "C" __global__ __launch_bounds__(256)
void k_sortids(const int* __restrict__ ei, int* __restrict__ cursor,
               int2* __restrict__ rc)
{
    int e = blockIdx.x * 256 + threadIdx.x;
    int r = ei[e], c = ei[NE + e];
    int slot = atomicAdd(&cursor[r], 1);
    rc[slot] = make_int2(r, c);
}

// ---------------------------------------------------------------------------
// Kernel 1: MFMA  [A|B] = bf16(h) @ Wab (+be1 on A half). Operand-swapped.
// ---------------------------------------------------------------------------
extern "C" __global__ __launch_bounds__(256)
void k_ab(const float* __restrict__ h, const ushort_t* __restrict__ WabT,
          const float* __restrict__ be1,
          ushort_t* __restrict__ A, ushort_t* __restrict__ B)
{
    __shared__ ushort_t hs[64][LPAD] __attribute__((aligned(16)));
    const int tid = threadIdx.x;
    const int n0 = blockIdx.x * 64;
    {
        int r = tid >> 2, seg = tid & 3;
        int n = n0 + r; if (n >= NN) n = n0;
        const float4* src = (const float4*)(h + (size_t)n * HD + seg * 32);
        uint2* dst = (uint2*)&hs[r][seg * 32];
#pragma unroll
        for (int i = 0; i < 8; i++) {
            float4 v = src[i];
            uint2 p; p.x = cvt_pk_bf16(v.x, v.y); p.y = cvt_pk_bf16(v.z, v.w);
            dst[i] = p;
        }
    }
    __syncthreads();
    const int wave = tid >> 6, lane = tid & 63;
    const int lr = lane & 15, lg = lane >> 4;
    f32x4 acc[16];
#pragma unroll
    for (int nt = 0; nt < 16; nt++) acc[nt] = (f32x4){0.f, 0.f, 0.f, 0.f};
#pragma unroll
    for (int ks = 0; ks < 4; ks++) {
        bf16x8 hf8 = *(const bf16x8*)&hs[wave * 16 + lr][ks * 32 + lg * 8];
#pragma unroll
        for (int nt = 0; nt < 16; nt++) {
            bf16x8 wf = *(const bf16x8*)(WabT + (size_t)(nt * 16 + lr) * HD + ks * 32 + lg * 8);
            acc[nt] = __builtin_amdgcn_mfma_f32_16x16x32_bf16(wf, hf8, acc[nt], 0, 0, 0);
        }
    }
    const int node = n0 + wave * 16 + lr;
    if (node < NN) {
#pragma unroll
        for (int nt = 0; nt < 16; nt++) {
            float4 bias = (nt < 8) ? ((const float4*)be1)[nt * 4 + lg]
                                   : (float4){0.f, 0.f, 0.f, 0.f};
            uint2 pk;
            pk.x = cvt_pk_bf16(acc[nt][0] + bias.x, acc[nt][1] + bias.y);
            pk.y = cvt_pk_bf16(acc[nt][2] + bias.z, acc[nt][3] + bias.w);
            if (nt < 8)
                *(uint2*)(A + (size_t)node * HD + nt * 16 + lg * 4) = pk;
            else
                *(uint2*)(B + (size_t)node * HD + (nt - 8) * 16 + lg * 4) = pk;
        }
    }
}

// ---------------------------------------------------------------------------
// Kernel 2: MFMA edge kernel, one 128-edge tile per block (sorted rc[]).
// Operand-swapped GEMMs; run-merged scatter; single barrier.
// ---------------------------------------------------------------------------
extern "C" __global__ __launch_bounds__(256, 4)
void k_edge(const int2* __restrict__ rc, const float* __restrict__ coord,
            const ushort_t* __restrict__ A, const ushort_t* __restrict__ B,
            const float* __restrict__ WeL, const float* __restrict__ be2,
            const ushort_t* __restrict__ We2T,
            const ushort_t* __restrict__ Wc1T,
            const float* __restrict__ bc1, const float* __restrict__ Wc2,
            float* __restrict__ agg_h, float* __restrict__ agg_c)
{
    __shared__ ushort_t m_lds[EB][LPAD] __attribute__((aligned(16)));
    __shared__ float cd_lds[EB][4];
    __shared__ int rows_s[EB];

    const int tid = threadIdx.x;
    const int e  = tid >> 1;       // edge slot 0..127 (sorted order)
    const int hf = tid & 1;        // feature half
    const int wave = tid >> 6, lane = tid & 63;
    const int lr = lane & 15, lg = lane >> 4;

    int2 rce = rc[blockIdx.x * EB + e];
    const int row = rce.x, col = rce.y;

    float c0 = coord[(size_t)row * 3 + 0] - coord[(size_t)col * 3 + 0];
    float c1 = coord[(size_t)row * 3 + 1] - coord[(size_t)col * 3 + 1];
    float c2 = coord[(size_t)row * 3 + 2] - coord[(size_t)col * 3 + 2];
    float radial = c0 * c0 + c1 * c1 + c2 * c2;
    if (hf == 0) {
        rows_s[e] = row;
        float inv = __builtin_amdgcn_rcpf(sqrtf(radial) + EPSV);
        cd_lds[e][0] = c0 * inv; cd_lds[e][1] = c1 * inv; cd_lds[e][2] = c2 * inv;
    }

    {
        const bf16x8* A8 = (const bf16x8*)(A + (size_t)row * HD + hf * 64);
        const bf16x8* B8 = (const bf16x8*)(B + (size_t)col * HD + hf * 64);
        const float4* WL4 = (const float4*)WeL + hf * 16;
#pragma unroll
        for (int i = 0; i < 8; i++) {
            bf16x8 av = A8[i], bv = B8[i];
            float4 w0 = WL4[2 * i], w1 = WL4[2 * i + 1];
            float v0 = silu_f(b2f((ushort_t)av[0]) + b2f((ushort_t)bv[0]) + radial * w0.x);
            float v1 = silu_f(b2f((ushort_t)av[1]) + b2f((ushort_t)bv[1]) + radial * w0.y);
            float v2 = silu_f(b2f((ushort_t)av[2]) + b2f((ushort_t)bv[2]) + radial * w0.z);
            float v3 = silu_f(b2f((ushort_t)av[3]) + b2f((ushort_t)bv[3]) + radial * w0.w);
            float v4 = silu_f(b2f((ushort_t)av[4]) + b2f((ushort_t)bv[4]) + radial * w1.x);
            float v5 = silu_f(b2f((ushort_t)av[5]) + b2f((ushort_t)bv[5]) + radial * w1.y);
            float v6 = silu_f(b2f((ushort_t)av[6]) + b2f((ushort_t)bv[6]) + radial * w1.z);
            float v7 = silu_f(b2f((ushort_t)av[7]) + b2f((ushort_t)bv[7]) + radial * w1.w);
            uint4 p;
            p.x = cvt_pk_bf16(v0, v1); p.y = cvt_pk_bf16(v2, v3);
            p.z = cvt_pk_bf16(v4, v5); p.w = cvt_pk_bf16(v6, v7);
            *(uint4*)&m_lds[e][hf * 64 + i * 8] = p;
        }
    }
    // no barrier: wave w wrote rows [32w,32w+32) and only reads those below

    // ---- GEMM1 (swapped): lane -> m[edge=lr(+16mt)][4 consecutive j] ----
    f32x4 acc[2][8];
#pragma unroll
    for (int mt = 0; mt < 2; mt++)
#pragma unroll
        for (int nt = 0; nt < 8; nt++) acc[mt][nt] = (f32x4){0.f, 0.f, 0.f, 0.f};
#pragma unroll
    for (int ks = 0; ks < 4; ks++) {
        bf16x8 mf0 = *(const bf16x8*)&m_lds[wave * 32 + lr][ks * 32 + lg * 8];
        bf16x8 mf1 = *(const bf16x8*)&m_lds[wave * 32 + 16 + lr][ks * 32 + lg * 8];
#pragma unroll
        for (int nt = 0; nt < 8; nt++) {
            bf16x8 wf = *(const bf16x8*)(We2T + (size_t)(nt * 16 + lr) * HD + ks * 32 + lg * 8);
            acc[0][nt] = __builtin_amdgcn_mfma_f32_16x16x32_bf16(wf, mf0, acc[0][nt], 0, 0, 0);
            acc[1][nt] = __builtin_amdgcn_mfma_f32_16x16x32_bf16(wf, mf1, acc[1][nt], 0, 0, 0);
        }
    }
    // m = silu(acc+be2) -> m_lds[edge][j], b64 packed (wave-local rows)
#pragma unroll
    for (int nt = 0; nt < 8; nt++) {
        float4 be2v = ((const float4*)be2)[nt * 4 + lg];
#pragma unroll
        for (int mt = 0; mt < 2; mt++) {
            float v0 = silu_f(acc[mt][nt][0] + be2v.x);
            float v1 = silu_f(acc[mt][nt][1] + be2v.y);
            float v2 = silu_f(acc[mt][nt][2] + be2v.z);
            float v3 = silu_f(acc[mt][nt][3] + be2v.w);
            uint2 pk; pk.x = cvt_pk_bf16(v0, v1); pk.y = cvt_pk_bf16(v2, v3);
            *(uint2*)&m_lds[wave * 32 + mt * 16 + lr][nt * 16 + lg * 4] = pk;
        }
    }

    // ---- GEMM2 (swapped): m @ Wc1 ----
#pragma unroll
    for (int mt = 0; mt < 2; mt++)
#pragma unroll
        for (int nt = 0; nt < 8; nt++) acc[mt][nt] = (f32x4){0.f, 0.f, 0.f, 0.f};
#pragma unroll
    for (int ks = 0; ks < 4; ks++) {
        bf16x8 mf0 = *(const bf16x8*)&m_lds[wave * 32 + lr][ks * 32 + lg * 8];
        bf16x8 mf1 = *(const bf16x8*)&m_lds[wave * 32 + 16 + lr][ks * 32 + lg * 8];
#pragma unroll
        for (int nt = 0; nt < 8; nt++) {
            bf16x8 wf = *(const bf16x8*)(Wc1T + (size_t)(nt * 16 + lr) * HD + ks * 32 + lg * 8);
            acc[0][nt] = __builtin_amdgcn_mfma_f32_16x16x32_bf16(wf, mf0, acc[0][nt], 0, 0, 0);
            acc[1][nt] = __builtin_amdgcn_mfma_f32_16x16x32_bf16(wf, mf1, acc[1][nt], 0, 0, 0);
        }
    }

    // phi partials over this lane's 4 consecutive j (x2 edges), 2 shuffles
    float ph0 = 0.f, ph1 = 0.f;
#pragma unroll
    for (int nt = 0; nt < 8; nt++) {
        float4 bc1v = ((const float4*)bc1)[nt * 4 + lg];
        float4 wc2v = ((const float4*)Wc2)[nt * 4 + lg];
        ph0 += silu_f(acc[0][nt][0] + bc1v.x) * wc2v.x
             + silu_f(acc[0][nt][1] + bc1v.y) * wc2v.y
             + silu_f(acc[0][nt][2] + bc1v.z) * wc2v.z
             + silu_f(acc[0][nt][3] + bc1v.w) * wc2v.w;
        ph1 += silu_f(acc[1][nt][0] + bc1v.x) * wc2v.x
             + silu_f(acc[1][nt][1] + bc1v.y) * wc2v.y
             + silu_f(acc[1][nt][2] + bc1v.z) * wc2v.z
             + silu_f(acc[1][nt][3] + bc1v.w) * wc2v.w;
    }
    ph0 += __shfl_xor(ph0, 16, 64); ph0 += __shfl_xor(ph0, 32, 64);
    ph1 += __shfl_xor(ph1, 16, 64); ph1 += __shfl_xor(ph1, 32, 64);
    if (lg == 0) {
        int e0 = wave * 32 + lr, e1 = e0 + 16;
        cd_lds[e0][0] *= ph0; cd_lds[e0][1] *= ph0; cd_lds[e0][2] *= ph0;
        cd_lds[e1][0] *= ph1; cd_lds[e1][1] *= ph1; cd_lds[e1][2] *= ph1;
    }

    __syncthreads();   // the only barrier: scatters read all waves' rows

    // ---- agg_h: run-merged scatter (rows sorted) ----
    {
        const int j = tid & 127, g = tid >> 7;
        const int es0 = g * 64, es1 = es0 + 64;
        float acc_r = 0.f;
        int cur = rows_s[es0];
        for (int es = es0; es < es1; es++) {
            int r = rows_s[es];
            if (r != cur) {
                atomicAdd(&agg_h[(size_t)cur * HD + j], acc_r);
                acc_r = 0.f; cur = r;
            }
            acc_r += b2f(m_lds[es][j]);
        }
        atomicAdd(&agg_h[(size_t)cur * HD + j], acc_r);
    }
    // ---- agg_c: run-merge, wave 0 only ----
    if (wave == 0) {
        int c = lane >> 4, sub = lane & 15;
        if (c < 3) {
            const int es0 = sub * 8, es1 = es0 + 8;
            float acc_r = 0.f;
            int cur = rows_s[es0];
            for (int es = es0; es < es1; es++) {
                int r = rows_s[es];
                if (r != cur) {
                    atomicAdd(&agg_c[(size_t)cur * 3 + c], acc_r);
                    acc_r = 0.f; cur = r;
                }
                acc_r += cd_lds[es][c];
            }
            atomicAdd(&agg_c[(size_t)cur * 3 + c], acc_r);
        }
    }
}

// ---------------------------------------------------------------------------
// Kernel 3: MFMA node MLP (operand-swapped), float4 residual epilogue.
// ---------------------------------------------------------------------------
extern "C" __global__ __launch_bounds__(256)
void k_node(const float* __restrict__ h, const ushort_t* __restrict__ Wn1T,
            const float* __restrict__ bn1, const ushort_t* __restrict__ Wn2T,
            const float* __restrict__ bn2, const float* __restrict__ coord,
            const int* __restrict__ deg,
            float* __restrict__ hout /* = agg_h in */,
            float* __restrict__ cout /* = agg_c in */)
{
    __shared__ ushort_t cs[64][CPAD] __attribute__((aligned(16)));
    __shared__ ushort_t us[64][LPAD] __attribute__((aligned(16)));
    const int tid = threadIdx.x;
    const int n0 = blockIdx.x * 64;
    {
        int r = tid >> 2, seg = tid & 3;
        int n = n0 + r; if (n >= NN) n = n0;
        const float4* s0 = (const float4*)(h + (size_t)n * HD + seg * 32);
        const float4* s1 = (const float4*)(hout + (size_t)n * HD + seg * 32);
        uint2* d0 = (uint2*)&cs[r][seg * 32];
        uint2* d1 = (uint2*)&cs[r][128 + seg * 32];
#pragma unroll
        for (int i = 0; i < 8; i++) {
            float4 v = s0[i];
            uint2 p; p.x = cvt_pk_bf16(v.x, v.y); p.y = cvt_pk_bf16(v.z, v.w);
            d0[i] = p;
            float4 w = s1[i];
            uint2 q; q.x = cvt_pk_bf16(w.x, w.y); q.y = cvt_pk_bf16(w.z, w.w);
            d1[i] = q;
        }
    }
    __syncthreads();
    const int wave = tid >> 6, lane = tid & 63;
    const int lr = lane & 15, lg = lane >> 4;

    // ---- GEMM1 (swapped): cat[64,256] @ Wn1 -> u ----
    f32x4 acc[8];
#pragma unroll
    for (int nt = 0; nt < 8; nt++) acc[nt] = (f32x4){0.f, 0.f, 0.f, 0.f};
#pragma unroll
    for (int ks = 0; ks < 8; ks++) {
        bf16x8 cf = *(const bf16x8*)&cs[wave * 16 + lr][ks * 32 + lg * 8];
#pragma unroll
        for (int nt = 0; nt < 8; nt++) {
            bf16x8 wf = *(const bf16x8*)(Wn1T + (size_t)(nt * 16 + lr) * 256 + ks * 32 + lg * 8);
            acc[nt] = __builtin_amdgcn_mfma_f32_16x16x32_bf16(wf, cf, acc[nt], 0, 0, 0);
        }
    }
#pragma unroll
    for (int nt = 0; nt < 8; nt++) {
        float4 b1 = ((const float4*)bn1)[nt * 4 + lg];
        float v0 = silu_f(acc[nt][0] + b1.x);
        float v1 = silu_f(acc[nt][1] + b1.y);
        float v2 = silu_f(acc[nt][2] + b1.z);
        float v3 = silu_f(acc[nt][3] + b1.w);
        uint2 pk; pk.x = cvt_pk_bf16(v0, v1); pk.y = cvt_pk_bf16(v2, v3);
        *(uint2*)&us[wave * 16 + lr][nt * 16 + lg * 4] = pk;
    }
    // wave-local rows -> no barrier

    // ---- GEMM2 (swapped): u[64,128] @ Wn2 ----
    f32x4 acc2[8];
#pragma unroll
    for (int nt = 0; nt < 8; nt++) acc2[nt] = (f32x4){0.f, 0.f, 0.f, 0.f};
#pragma unroll
    for (int ks = 0; ks < 4; ks++) {
        bf16x8 uf = *(const bf16x8*)&us[wave * 16 + lr][ks * 32 + lg * 8];
#pragma unroll
        for (int nt = 0; nt < 8; nt++) {
            bf16x8 wf = *(const bf16x8*)(Wn2T + (size_t)(nt * 16 + lr) * HD + ks * 32 + lg * 8);
            acc2[nt] = __builtin_amdgcn_mfma_f32_16x16x32_bf16(wf, uf, acc2[nt], 0, 0, 0);
        }
    }
    const int node = n0 + wave * 16 + lr;
    if (node < NN) {
#pragma unroll
        for (int nt = 0; nt < 8; nt++) {
            float4 b2 = ((const float4*)bn2)[nt * 4 + lg];
            size_t idx = (size_t)node * HD + nt * 16 + lg * 4;
            float4 hv = *(const float4*)(h + idx);
            float4 o;
            o.x = hv.x + acc2[nt][0] + b2.x;
            o.y = hv.y + acc2[nt][1] + b2.y;
            o.z = hv.z + acc2[nt][2] + b2.z;
            o.w = hv.w + acc2[nt][3] + b2.w;
            *(float4*)(hout + idx) = o;
        }
        if (lg == 0) {
            float invc = __builtin_amdgcn_rcpf(fmaxf((float)deg[node], 1.0f));
#pragma unroll
            for (int i = 0; i < 3; i++) {
                size_t idx = (size_t)node * 3 + i;
                cout[idx] = coord[idx] + cout[idx] * invc;
            }
        }
    }
}

// ---------------------------------------------------------------------------
extern "C" void kernel_launch(void* const* d_in, const int* in_sizes, int n_in,
                              void* d_out, int out_size, void* d_ws, size_t ws_size,
                              hipStream_t stream)
{
    const float* h     = (const float*)d_in[0];
    const int*   ei    = (const int*)d_in[1];
    const float* coord = (const float*)d_in[2];
    const float* We1   = (const float*)d_in[3];
    const float* be1   = (const float*)d_in[4];
    const float* We2   = (const float*)d_in[5];
    const float* be2   = (const float*)d_in[6];
    const float* Wn1   = (const float*)d_in[7];
    const float* bn1   = (const float*)d_in[8];
    const float* Wn2   = (const float*)d_in[9];
    const float* bn2   = (const float*)d_in[10];
    const float* Wc1   = (const float*)d_in[11];
    const float* bc1   = (const float*)d_in[12];
    const float* Wc2   = (const float*)d_in[13];

    float* out   = (float*)d_out;
    float* agg_h = out;                         // [NN,128] accum, then h_out
    float* agg_c = out + (size_t)NN * HD;       // [NN,3]  accum, then coord_out

    ushort_t* A    = (ushort_t*)d_ws;            // [NN,128] bf16
    ushort_t* B    = A + (size_t)NN * HD;        // [NN,128] bf16
    ushort_t* We2T = B + (size_t)NN * HD;        // [128,128]
    ushort_t* Wc1T = We2T + 16384;               // [128,128]
    ushort_t* WabT = Wc1T + 16384;               // [256,128]
    ushort_t* Wn1T = WabT + 32768;               // [128,256]
    ushort_t* Wn2T = Wn1T + 32768;               // [128,128]
    int* deg    = (int*)(Wn2T + 16384);          // [NN]
    int* cursor = deg + NN;                      // [NN]
    int* bsum   = cursor + NN;                   // [98]
    int* boff   = bsum + 128;                    // [98]
    int2* rc    = (int2*)(boff + 128);           // [NE] pre-gathered (row,col)
    const float* WeL = We1 + (size_t)2 * HD * HD;

    const int scan_nb = (NN + 1023) / 1024;      // 98

    hipMemsetAsync(d_out, 0, (size_t)out_size * sizeof(float), stream);
    hipMemsetAsync(deg, 0, (size_t)NN * sizeof(int), stream);

    k_prep<<<448, 256, 0, stream>>>(We2, Wc1, We1, Wn1, Wn2,
                                    We2T, Wc1T, WabT, Wn1T, Wn2T);
    k_hist<<<NE / 256, 256, 0, stream>>>(ei, deg);
    k_ab<<<(NN + 63) / 64, 256, 0, stream>>>(h, WabT, be1, A, B);
    k_scan1<<<scan_nb, 1024, 0, stream>>>(deg, bsum);
    k_scan2<<<1, 128, 0, stream>>>(bsum, boff, scan_nb);
    k_scan3<<<scan_nb, 1024, 0, stream>>>(deg, boff, cursor);
    k_sortids<<<NE / 256, 256, 0, stream>>>(ei, cursor, rc);
    k_edge<<<NE / EB, 256, 0, stream>>>(rc, coord, A, B, WeL, be2,
                                        We2T, Wc1T, bc1, Wc2, agg_h, agg_c);
    k_node<<<(NN + 63) / 64, 256, 0, stream>>>(h, Wn1T, bn1, Wn2T, bn2, coord,
                                               deg, agg_h, agg_c);
}

// Round 8
// 889.129 us; speedup vs baseline: 1.6030x; 1.1738x over previous
//
#include <hip/hip_runtime.h>

#define NN 100000
#define NE 1600000
#define HD 128
#define EPSV 1e-8f
#define EB 64       // edges per block (k_edge)
#define LPAD 136    // padded LDS row (bf16 elems): 272 B, 16B-aligned
#define CPAD 264    // padded row for 256-wide concat tile

typedef unsigned short ushort_t;
typedef __attribute__((ext_vector_type(8))) short bf16x8;
typedef __attribute__((ext_vector_type(4))) float f32x4;

__device__ __forceinline__ float silu_f(float x) {
    return x * __builtin_amdgcn_rcpf(1.0f + __expf(-x));
}
__device__ __forceinline__ float b2f(unsigned short u) {
    union { unsigned int i; float f; } v; v.i = ((unsigned int)u) << 16; return v.f;
}
__device__ __forceinline__ unsigned short f2b(float f) {
    union { float f; unsigned int i; } v; v.f = f;
    unsigned int r = v.i + 0x7fff + ((v.i >> 16) & 1);
    return (unsigned short)(r >> 16);
}
__device__ __forceinline__ unsigned int cvt_pk_bf16(float lo, float hi) {
    unsigned int r;
    asm("v_cvt_pk_bf16_f32 %0, %1, %2" : "=v"(r) : "v"(lo), "v"(hi));
    return r;
}

// ---------------------------------------------------------------------------
// Kernel 0: build bf16 transposed weight tables.
// ---------------------------------------------------------------------------
extern "C" __global__ __launch_bounds__(256)
void k_prep(const float* __restrict__ We2, const float* __restrict__ Wc1,
            const float* __restrict__ We1, const float* __restrict__ Wn1,
            const float* __restrict__ Wn2,
            ushort_t* __restrict__ We2T, ushort_t* __restrict__ Wc1T,
            ushort_t* __restrict__ WabT, ushort_t* __restrict__ Wn1T,
            ushort_t* __restrict__ Wn2T)
{
    int id = blockIdx.x * 256 + threadIdx.x;
    if (id < 16384) {
        int n = id >> 7, k = id & 127;
        We2T[id] = f2b(We2[k * HD + n]);
    } else if (id < 32768) {
        int r = id - 16384; int n = r >> 7, k = r & 127;
        Wc1T[r] = f2b(Wc1[k * HD + n]);
    } else if (id < 65536) {
        int r = id - 32768; int j = r >> 7, k = r & 127;
        float v = (j < 128) ? We1[k * HD + j] : We1[(size_t)(128 + k) * HD + (j - 128)];
        WabT[r] = f2b(v);
    } else if (id < 98304) {
        int r = id - 65536; int j = r >> 8, k = r & 255;
        Wn1T[r] = f2b(Wn1[(size_t)k * HD + j]);
    } else if (id < 114688) {
        int r = id - 98304; int j = r >> 7, k = r & 127;
        Wn2T[r] = f2b(Wn2[k * HD + j]);
    }
}

// ---------------------------------------------------------------------------
// Sort: histogram -> 3-kernel parallel scan -> scatter pre-gathered (row,col)
// ---------------------------------------------------------------------------
extern "C" __global__ __launch_bounds__(256)
void k_hist(const int* __restrict__ ei, int* __restrict__ deg)
{
    int e = blockIdx.x * 256 + threadIdx.x;
    atomicAdd(&deg[ei[e]], 1);
}

extern "C" __global__ __launch_bounds__(1024)
void k_scan1(const int* __restrict__ deg, int* __restrict__ bsum)
{
    __shared__ int wsum[16];
    const int tid = threadIdx.x;
    const int lane = tid & 63, w = tid >> 6;
    int i = blockIdx.x * 1024 + tid;
    int v = (i < NN) ? deg[i] : 0;
#pragma unroll
    for (int off = 32; off > 0; off >>= 1) v += __shfl_xor(v, off, 64);
    if (lane == 0) wsum[w] = v;
    __syncthreads();
    if (tid == 0) {
        int s = 0;
#pragma unroll
        for (int k = 0; k < 16; k++) s += wsum[k];
        bsum[blockIdx.x] = s;
    }
}

extern "C" __global__ __launch_bounds__(128)
void k_scan2(const int* __restrict__ bsum, int* __restrict__ boff, int nb)
{
    __shared__ int wsum2[2];
    const int tid = threadIdx.x;
    const int lane = tid & 63, w = tid >> 6;
    int v = (tid < nb) ? bsum[tid] : 0;
    int s = v;
#pragma unroll
    for (int off = 1; off < 64; off <<= 1) {
        int t = __shfl_up(s, off, 64);
        if (lane >= off) s += t;
    }
    if (lane == 63) wsum2[w] = s;
    __syncthreads();
    int excl = ((w == 1) ? wsum2[0] : 0) + s - v;
    if (tid < nb) boff[tid] = excl;
}

extern "C" __global__ __launch_bounds__(1024)
void k_scan3(const int* __restrict__ deg, const int* __restrict__ boff,
             int* __restrict__ cursor)
{
    __shared__ int wsum[16];
    const int tid = threadIdx.x;
    const int lane = tid & 63, w = tid >> 6;
    int i = blockIdx.x * 1024 + tid;
    int v = (i < NN) ? deg[i] : 0;
    int s = v;
#pragma unroll
    for (int off = 1; off < 64; off <<= 1) {
        int t = __shfl_up(s, off, 64);
        if (lane >= off) s += t;
    }
    if (lane == 63) wsum[w] = s;
    __syncthreads();
    if (w == 0) {
        int ws = (lane < 16) ? wsum[lane] : 0;
#pragma unroll
        for (int off = 1; off < 16; off <<= 1) {
            int t = __shfl_up(ws, off, 64);
            if (lane >= off) ws += t;
        }
        if (lane < 16) wsum[lane] = ws;
    }
    __syncthreads();
    int excl = boff[blockIdx.x] + ((w > 0) ? wsum[w - 1] : 0) + s - v;
    if (i < NN) cursor[i] = excl;
}

extern "C" __global__ __launch_bounds__(256)
void k_sortids(const int* __restrict__ ei, int* __restrict__ cursor,
               int2* __restrict__ rc)
{
    int e = blockIdx.x * 256 + threadIdx.x;
    int r = ei[e], c = ei[NE + e];
    int slot = atomicAdd(&cursor[r], 1);
    rc[slot] = make_int2(r, c);
}

// ---------------------------------------------------------------------------
// Kernel 1: MFMA  [A|B] = bf16(h) @ Wab (+be1 on A half). Operand-swapped.
// ---------------------------------------------------------------------------
extern "C" __global__ __launch_bounds__(256)
void k_ab(const float* __restrict__ h, const ushort_t* __restrict__ WabT,
          const float* __restrict__ be1,
          ushort_t* __restrict__ A, ushort_t* __restrict__ B)
{
    __shared__ ushort_t hs[64][LPAD] __attribute__((aligned(16)));
    const int tid = threadIdx.x;
    const int n0 = blockIdx.x * 64;
    {
        int r = tid >> 2, seg = tid & 3;
        int n = n0 + r; if (n >= NN) n = n0;
        const float4* src = (const float4*)(h + (size_t)n * HD + seg * 32);
        uint2* dst = (uint2*)&hs[r][seg * 32];
#pragma unroll
        for (int i = 0; i < 8; i++) {
            float4 v = src[i];
            uint2 p; p.x = cvt_pk_bf16(v.x, v.y); p.y = cvt_pk_bf16(v.z, v.w);
            dst[i] = p;
        }
    }
    __syncthreads();
    const int wave = tid >> 6, lane = tid & 63;
    const int lr = lane & 15, lg = lane >> 4;
    f32x4 acc[16];
#pragma unroll
    for (int nt = 0; nt < 16; nt++) acc[nt] = (f32x4){0.f, 0.f, 0.f, 0.f};
#pragma unroll
    for (int ks = 0; ks < 4; ks++) {
        bf16x8 hf8 = *(const bf16x8*)&hs[wave * 16 + lr][ks * 32 + lg * 8];
#pragma unroll
        for (int nt = 0; nt < 16; nt++) {
            bf16x8 wf = *(const bf16x8*)(WabT + (size_t)(nt * 16 + lr) * HD + ks * 32 + lg * 8);
            acc[nt] = __builtin_amdgcn_mfma_f32_16x16x32_bf16(wf, hf8, acc[nt], 0, 0, 0);
        }
    }
    const int node = n0 + wave * 16 + lr;
    if (node < NN) {
#pragma unroll
        for (int nt = 0; nt < 16; nt++) {
            float4 bias = (nt < 8) ? ((const float4*)be1)[nt * 4 + lg]
                                   : (float4){0.f, 0.f, 0.f, 0.f};
            uint2 pk;
            pk.x = cvt_pk_bf16(acc[nt][0] + bias.x, acc[nt][1] + bias.y);
            pk.y = cvt_pk_bf16(acc[nt][2] + bias.z, acc[nt][3] + bias.w);
            if (nt < 8)
                *(uint2*)(A + (size_t)node * HD + nt * 16 + lg * 4) = pk;
            else
                *(uint2*)(B + (size_t)node * HD + (nt - 8) * 16 + lg * 4) = pk;
        }
    }
}

// ---------------------------------------------------------------------------
// Kernel 2: MFMA edge kernel, one 64-edge tile per 128-thread block.
// 8 blocks/CU (20480B LDS). Biases + WeL staged in LDS (broadcast reads).
// Swapped-operand GEMMs; run-merged scatter.
// ---------------------------------------------------------------------------
extern "C" __global__ __launch_bounds__(128, 4)
void k_edge(const int2* __restrict__ rc, const float* __restrict__ coord,
            const ushort_t* __restrict__ A, const ushort_t* __restrict__ B,
            const float* __restrict__ WeL, const float* __restrict__ be2,
            const ushort_t* __restrict__ We2T,
            const ushort_t* __restrict__ Wc1T,
            const float* __restrict__ bc1, const float* __restrict__ Wc2,
            float* __restrict__ agg_h, float* __restrict__ agg_c)
{
    __shared__ ushort_t m_lds[EB][LPAD] __attribute__((aligned(16)));  // 17408
    __shared__ float cd_lds[EB][3];                                    // 768
    __shared__ int rows_s[EB];                                         // 256
    __shared__ float bias_lds[384] __attribute__((aligned(16)));       // be2|bc1|Wc2
    __shared__ float wel_lds[128] __attribute__((aligned(16)));        // 512

    const int tid = threadIdx.x;
    const int e  = tid >> 1;       // edge slot 0..63 (sorted order)
    const int hf = tid & 1;        // feature half
    const int wave = tid >> 6, lane = tid & 63;
    const int lr = lane & 15, lg = lane >> 4;

    // ---- stage biases + WeL into LDS ----
    {
        int i = tid;
        bias_lds[i]       = (i < 128) ? be2[i] : 0.f;   // fill below
        bias_lds[128 + i] = bc1[i];
        if (i < 128) bias_lds[256 + i] = Wc2[i];
        wel_lds[i] = WeL[i];
    }
    // fix be2 upper half (tid covers 0..127 only; be2 is 128 wide: done)
    int2 rce = rc[blockIdx.x * EB + e];
    const int row = rce.x, col = rce.y;

    float c0 = coord[(size_t)row * 3 + 0] - coord[(size_t)col * 3 + 0];
    float c1 = coord[(size_t)row * 3 + 1] - coord[(size_t)col * 3 + 1];
    float c2 = coord[(size_t)row * 3 + 2] - coord[(size_t)col * 3 + 2];
    float radial = c0 * c0 + c1 * c1 + c2 * c2;
    if (hf == 0) {
        rows_s[e] = row;
        float inv = __builtin_amdgcn_rcpf(sqrtf(radial) + EPSV);
        cd_lds[e][0] = c0 * inv; cd_lds[e][1] = c1 * inv; cd_lds[e][2] = c2 * inv;
    }
    __syncthreads();   // bias_lds/wel_lds ready

    {
        const bf16x8* A8 = (const bf16x8*)(A + (size_t)row * HD + hf * 64);
        const bf16x8* B8 = (const bf16x8*)(B + (size_t)col * HD + hf * 64);
        const float4* WL4 = (const float4*)wel_lds + hf * 16;
#pragma unroll
        for (int i = 0; i < 8; i++) {
            bf16x8 av = A8[i], bv = B8[i];
            float4 w0 = WL4[2 * i], w1 = WL4[2 * i + 1];
            float v0 = silu_f(b2f((ushort_t)av[0]) + b2f((ushort_t)bv[0]) + radial * w0.x);
            float v1 = silu_f(b2f((ushort_t)av[1]) + b2f((ushort_t)bv[1]) + radial * w0.y);
            float v2 = silu_f(b2f((ushort_t)av[2]) + b2f((ushort_t)bv[2]) + radial * w0.z);
            float v3 = silu_f(b2f((ushort_t)av[3]) + b2f((ushort_t)bv[3]) + radial * w0.w);
            float v4 = silu_f(b2f((ushort_t)av[4]) + b2f((ushort_t)bv[4]) + radial * w1.x);
            float v5 = silu_f(b2f((ushort_t)av[5]) + b2f((ushort_t)bv[5]) + radial * w1.y);
            float v6 = silu_f(b2f((ushort_t)av[6]) + b2f((ushort_t)bv[6]) + radial * w1.z);
            float v7 = silu_f(b2f((ushort_t)av[7]) + b2f((ushort_t)bv[7]) + radial * w1.w);
            uint4 p;
            p.x = cvt_pk_bf16(v0, v1); p.y = cvt_pk_bf16(v2, v3);
            p.z = cvt_pk_bf16(v4, v5); p.w = cvt_pk_bf16(v6, v7);
            *(uint4*)&m_lds[e][hf * 64 + i * 8] = p;
        }
    }
    // no barrier: wave w wrote rows [32w,32w+32) and only reads those below

    // ---- GEMM1 (swapped): lane -> m[edge=lr(+16mt)][4 consecutive j] ----
    f32x4 acc[2][8];
#pragma unroll
    for (int mt = 0; mt < 2; mt++)
#pragma unroll
        for (int nt = 0; nt < 8; nt++) acc[mt][nt] = (f32x4){0.f, 0.f, 0.f, 0.f};
#pragma unroll
    for (int ks = 0; ks < 4; ks++) {
        bf16x8 mf0 = *(const bf16x8*)&m_lds[wave * 32 + lr][ks * 32 + lg * 8];
        bf16x8 mf1 = *(const bf16x8*)&m_lds[wave * 32 + 16 + lr][ks * 32 + lg * 8];
#pragma unroll
        for (int nt = 0; nt < 8; nt++) {
            bf16x8 wf = *(const bf16x8*)(We2T + (size_t)(nt * 16 + lr) * HD + ks * 32 + lg * 8);
            acc[0][nt] = __builtin_amdgcn_mfma_f32_16x16x32_bf16(wf, mf0, acc[0][nt], 0, 0, 0);
            acc[1][nt] = __builtin_amdgcn_mfma_f32_16x16x32_bf16(wf, mf1, acc[1][nt], 0, 0, 0);
        }
    }
    // m = silu(acc+be2) -> m_lds[edge][j], b64 packed (wave-local rows)
#pragma unroll
    for (int nt = 0; nt < 8; nt++) {
        float4 be2v = *(const float4*)&bias_lds[nt * 16 + lg * 4];
#pragma unroll
        for (int mt = 0; mt < 2; mt++) {
            float v0 = silu_f(acc[mt][nt][0] + be2v.x);
            float v1 = silu_f(acc[mt][nt][1] + be2v.y);
            float v2 = silu_f(acc[mt][nt][2] + be2v.z);
            float v3 = silu_f(acc[mt][nt][3] + be2v.w);
            uint2 pk; pk.x = cvt_pk_bf16(v0, v1); pk.y = cvt_pk_bf16(v2, v3);
            *(uint2*)&m_lds[wave * 32 + mt * 16 + lr][nt * 16 + lg * 4] = pk;
        }
    }

    // ---- GEMM2 (swapped): m @ Wc1 ----
#pragma unroll
    for (int mt = 0; mt < 2; mt++)
#pragma unroll
        for (int nt = 0; nt < 8; nt++) acc[mt][nt] = (f32x4){0.f, 0.f, 0.f, 0.f};
#pragma unroll
    for (int ks = 0; ks < 4; ks++) {
        bf16x8 mf0 = *(const bf16x8*)&m_lds[wave * 32 + lr][ks * 32 + lg * 8];
        bf16x8 mf1 = *(const bf16x8*)&m_lds[wave * 32 + 16 + lr][ks * 32 + lg * 8];
#pragma unroll
        for (int nt = 0; nt < 8; nt++) {
            bf16x8 wf = *(const bf16x8*)(Wc1T + (size_t)(nt * 16 + lr) * HD + ks * 32 + lg * 8);
            acc[0][nt] = __builtin_amdgcn_mfma_f32_16x16x32_bf16(wf, mf0, acc[0][nt], 0, 0, 0);
            acc[1][nt] = __builtin_amdgcn_mfma_f32_16x16x32_bf16(wf, mf1, acc[1][nt], 0, 0, 0);
        }
    }

    // phi partials over this lane's 4 consecutive j (x2 edges), 2 shuffles
    float ph0 = 0.f, ph1 = 0.f;
#pragma unroll
    for (int nt = 0; nt < 8; nt++) {
        float4 bc1v = *(const float4*)&bias_lds[128 + nt * 16 + lg * 4];
        float4 wc2v = *(const float4*)&bias_lds[256 + nt * 16 + lg * 4];
        ph0 += silu_f(acc[0][nt][0] + bc1v.x) * wc2v.x
             + silu_f(acc[0][nt][1] + bc1v.y) * wc2v.y
             + silu_f(acc[0][nt][2] + bc1v.z) * wc2v.z
             + silu_f(acc[0][nt][3] + bc1v.w) * wc2v.w;
        ph1 += silu_f(acc[1][nt][0] + bc1v.x) * wc2v.x
             + silu_f(acc[1][nt][1] + bc1v.y) * wc2v.y
             + silu_f(acc[1][nt][2] + bc1v.z) * wc2v.z
             + silu_f(acc[1][nt][3] + bc1v.w) * wc2v.w;
    }
    ph0 += __shfl_xor(ph0, 16, 64); ph0 += __shfl_xor(ph0, 32, 64);
    ph1 += __shfl_xor(ph1, 16, 64); ph1 += __shfl_xor(ph1, 32, 64);
    if (lg == 0) {
        int e0 = wave * 32 + lr, e1 = e0 + 16;
        cd_lds[e0][0] *= ph0; cd_lds[e0][1] *= ph0; cd_lds[e0][2] *= ph0;
        cd_lds[e1][0] *= ph1; cd_lds[e1][1] *= ph1; cd_lds[e1][2] *= ph1;
    }

    __syncthreads();   // scatters read all waves' rows

    // ---- agg_h: run-merged scatter (rows sorted); j = tid, es walks 0..63 ----
    {
        const int j = tid;
        float acc_r = 0.f;
        int cur = rows_s[0];
        for (int es = 0; es < EB; es++) {
            int r = rows_s[es];
            if (r != cur) {
                atomicAdd(&agg_h[(size_t)cur * HD + j], acc_r);
                acc_r = 0.f; cur = r;
            }
            acc_r += b2f(m_lds[es][j]);
        }
        atomicAdd(&agg_h[(size_t)cur * HD + j], acc_r);
    }
    // ---- agg_c: run-merge, wave 0 only (3 comps x 16 segments of 4) ----
    if (wave == 0) {
        int c = lane >> 4, sub = lane & 15;
        if (c < 3) {
            const int es0 = sub * 4, es1 = es0 + 4;
            float acc_r = 0.f;
            int cur = rows_s[es0];
            for (int es = es0; es < es1; es++) {
                int r = rows_s[es];
                if (r != cur) {
                    atomicAdd(&agg_c[(size_t)cur * 3 + c], acc_r);
                    acc_r = 0.f; cur = r;
                }
                acc_r += cd_lds[es][c];
            }
            atomicAdd(&agg_c[(size_t)cur * 3 + c], acc_r);
        }
    }
}

// ---------------------------------------------------------------------------
// Kernel 3: MFMA node MLP (operand-swapped), float4 residual epilogue.
// ---------------------------------------------------------------------------
extern "C" __global__ __launch_bounds__(256)
void k_node(const float* __restrict__ h, const ushort_t* __restrict__ Wn1T,
            const float* __restrict__ bn1, const ushort_t* __restrict__ Wn2T,
            const float* __restrict__ bn2, const float* __restrict__ coord,
            const int* __restrict__ deg,
            float* __restrict__ hout /* = agg_h in */,
            float* __restrict__ cout /* = agg_c in */)
{
    __shared__ ushort_t cs[64][CPAD] __attribute__((aligned(16)));
    __shared__ ushort_t us[64][LPAD] __attribute__((aligned(16)));
    const int tid = threadIdx.x;
    const int n0 = blockIdx.x * 64;
    {
        int r = tid >> 2, seg = tid & 3;
        int n = n0 + r; if (n >= NN) n = n0;
        const float4* s0 = (const float4*)(h + (size_t)n * HD + seg * 32);
        const float4* s1 = (const float4*)(hout + (size_t)n * HD + seg * 32);
        uint2* d0 = (uint2*)&cs[r][seg * 32];
        uint2* d1 = (uint2*)&cs[r][128 + seg * 32];
#pragma unroll
        for (int i = 0; i < 8; i++) {
            float4 v = s0[i];
            uint2 p; p.x = cvt_pk_bf16(v.x, v.y); p.y = cvt_pk_bf16(v.z, v.w);
            d0[i] = p;
            float4 w = s1[i];
            uint2 q; q.x = cvt_pk_bf16(w.x, w.y); q.y = cvt_pk_bf16(w.z, w.w);
            d1[i] = q;
        }
    }
    __syncthreads();
    const int wave = tid >> 6, lane = tid & 63;
    const int lr = lane & 15, lg = lane >> 4;

    // ---- GEMM1 (swapped): cat[64,256] @ Wn1 -> u ----
    f32x4 acc[8];
#pragma unroll
    for (int nt = 0; nt < 8; nt++) acc[nt] = (f32x4){0.f, 0.f, 0.f, 0.f};
#pragma unroll
    for (int ks = 0; ks < 8; ks++) {
        bf16x8 cf = *(const bf16x8*)&cs[wave * 16 + lr][ks * 32 + lg * 8];
#pragma unroll
        for (int nt = 0; nt < 8; nt++) {
            bf16x8 wf = *(const bf16x8*)(Wn1T + (size_t)(nt * 16 + lr) * 256 + ks * 32 + lg * 8);
            acc[nt] = __builtin_amdgcn_mfma_f32_16x16x32_bf16(wf, cf, acc[nt], 0, 0, 0);
        }
    }
#pragma unroll
    for (int nt = 0; nt < 8; nt++) {
        float4 b1 = ((const float4*)bn1)[nt * 4 + lg];
        float v0 = silu_f(acc[nt][0] + b1.x);
        float v1 = silu_f(acc[nt][1] + b1.y);
        float v2 = silu_f(acc[nt][2] + b1.z);
        float v3 = silu_f(acc[nt][3] + b1.w);
        uint2 pk; pk.x = cvt_pk_bf16(v0, v1); pk.y = cvt_pk_bf16(v2, v3);
        *(uint2*)&us[wave * 16 + lr][nt * 16 + lg * 4] = pk;
    }
    // wave-local rows -> no barrier

    // ---- GEMM2 (swapped): u[64,128] @ Wn2 ----
    f32x4 acc2[8];
#pragma unroll
    for (int nt = 0; nt < 8; nt++) acc2[nt] = (f32x4){0.f, 0.f, 0.f, 0.f};
#pragma unroll
    for (int ks = 0; ks < 4; ks++) {
        bf16x8 uf = *(const bf16x8*)&us[wave * 16 + lr][ks * 32 + lg * 8];
#pragma unroll
        for (int nt = 0; nt < 8; nt++) {
            bf16x8 wf = *(const bf16x8*)(Wn2T + (size_t)(nt * 16 + lr) * HD + ks * 32 + lg * 8);
            acc2[nt] = __builtin_amdgcn_mfma_f32_16x16x32_bf16(wf, uf, acc2[nt], 0, 0, 0);
        }
    }
    const int node = n0 + wave * 16 + lr;
    if (node < NN) {
#pragma unroll
        for (int nt = 0; nt < 8; nt++) {
            float4 b2 = ((const float4*)bn2)[nt * 4 + lg];
            size_t idx = (size_t)node * HD + nt * 16 + lg * 4;
            float4 hv = *(const float4*)(h + idx);
            float4 o;
            o.x = hv.x + acc2[nt][0] + b2.x;
            o.y = hv.y + acc2[nt][1] + b2.y;
            o.z = hv.z + acc2[nt][2] + b2.z;
            o.w = hv.w + acc2[nt][3] + b2.w;
            *(float4*)(hout + idx) = o;
        }
        if (lg == 0) {
            float invc = __builtin_amdgcn_rcpf(fmaxf((float)deg[node], 1.0f));
#pragma unroll
            for (int i = 0; i < 3; i++) {
                size_t idx = (size_t)node * 3 + i;
                cout[idx] = coord[idx] + cout[idx] * invc;
            }
        }
    }
}

// ---------------------------------------------------------------------------
extern "C" void kernel_launch(void* const* d_in, const int* in_sizes, int n_in,
                              void* d_out, int out_size, void* d_ws, size_t ws_size,
                              hipStream_t stream)
{
    const float* h     = (const float*)d_in[0];
    const int*   ei    = (const int*)d_in[1];
    const float* coord = (const float*)d_in[2];
    const float* We1   = (const float*)d_in[3];
    const float* be1   = (const float*)d_in[4];
    const float* We2   = (const float*)d_in[5];
    const float* be2   = (const float*)d_in[6];
    const float* Wn1   = (const float*)d_in[7];
    const float* bn1   = (const float*)d_in[8];
    const float* Wn2   = (const float*)d_in[9];
    const float* bn2   = (const float*)d_in[10];
    const float* Wc1   = (const float*)d_in[11];
    const float* bc1   = (const float*)d_in[12];
    const float* Wc2   = (const float*)d_in[13];

    float* out   = (float*)d_out;
    float* agg_h = out;                         // [NN,128] accum, then h_out
    float* agg_c = out + (size_t)NN * HD;       // [NN,3]  accum, then coord_out

    ushort_t* A    = (ushort_t*)d_ws;            // [NN,128] bf16
    ushort_t* B    = A + (size_t)NN * HD;        // [NN,128] bf16
    ushort_t* We2T = B + (size_t)NN * HD;        // [128,128]
    ushort_t* Wc1T = We2T + 16384;               // [128,128]
    ushort_t* WabT = Wc1T + 16384;               // [256,128]
    ushort_t* Wn1T = WabT + 32768;               // [128,256]
    ushort_t* Wn2T = Wn1T + 32768;               // [128,128]
    int* deg    = (int*)(Wn2T + 16384);          // [NN]
    int* cursor = deg + NN;                      // [NN]
    int* bsum   = cursor + NN;                   // [98]
    int* boff   = bsum + 128;                    // [98]
    int2* rc    = (int2*)(boff + 128);           // [NE] pre-gathered (row,col)
    const float* WeL = We1 + (size_t)2 * HD * HD;

    const int scan_nb = (NN + 1023) / 1024;      // 98

    hipMemsetAsync(d_out, 0, (size_t)out_size * sizeof(float), stream);
    hipMemsetAsync(deg, 0, (size_t)NN * sizeof(int), stream);

    k_prep<<<448, 256, 0, stream>>>(We2, Wc1, We1, Wn1, Wn2,
                                    We2T, Wc1T, WabT, Wn1T, Wn2T);
    k_hist<<<NE / 256, 256, 0, stream>>>(ei, deg);
    k_ab<<<(NN + 63) / 64, 256, 0, stream>>>(h, WabT, be1, A, B);
    k_scan1<<<scan_nb, 1024, 0, stream>>>(deg, bsum);
    k_scan2<<<1, 128, 0, stream>>>(bsum, boff, scan_nb);
    k_scan3<<<scan_nb, 1024, 0, stream>>>(deg, boff, cursor);
    k_sortids<<<NE / 256, 256, 0, stream>>>(ei, cursor, rc);
    k_edge<<<NE / EB, 128, 0, stream>>>(rc, coord, A, B, WeL, be2,
                                        We2T, Wc1T, bc1, Wc2, agg_h, agg_c);
    k_node<<<(NN + 63) / 64, 256, 0, stream>>>(h, Wn1T, bn1, Wn2T, bn2, coord,
                                               deg, agg_h, agg_c);
}